// Round 5
// baseline (315.312 us; speedup 1.0000x reference)
//
#include <hip/hip_runtime.h>
#include <cstdint>
#include <cstddef>

typedef unsigned short USHORT;
typedef __bf16 bf16x8 __attribute__((ext_vector_type(8)));
typedef float f32x4 __attribute__((ext_vector_type(4)));

__device__ __forceinline__ float b2f(USHORT u) {
    union { unsigned int i; float f; } v; v.i = ((unsigned int)u) << 16; return v.f;
}
__device__ __forceinline__ USHORT f2bf(float f) {
    union { float f; unsigned int i; } v; v.f = f;
    unsigned int u = v.i;
    unsigned int r = (u + 0x7FFFu + ((u >> 16) & 1u)) >> 16;
    return (USHORT)r;
}
__device__ __forceinline__ float fexp2(float x) { return __builtin_amdgcn_exp2f(x); }

__device__ __forceinline__ void gload_lds16(const void* g, void* l) {
    __builtin_amdgcn_global_load_lds(
        (const __attribute__((address_space(1))) void*)(uintptr_t)g,
        (__attribute__((address_space(3))) void*)(uint32_t)(uintptr_t)l,
        16, 0, 0);
}

// ---------------- f32 -> bf16 conversion (weights), 4 elems/thread ----------
__global__ __launch_bounds__(256)
void f2b_kernel(const float* __restrict__ src, USHORT* __restrict__ dst, int n)
{
    int i = (blockIdx.x * 256 + threadIdx.x) * 4;
    if (i < n) {
        float4 v = *(const float4*)(src + i);
        ushort4 o;
        o.x = f2bf(v.x); o.y = f2bf(v.y); o.z = f2bf(v.z); o.w = f2bf(v.w);
        *(ushort4*)(dst + i) = o;
    }
}

// ---------------- LayerNorm: f32 in -> bf16 out. 1 block/token, 256 thr ----
__global__ __launch_bounds__(256)
void ln_kernel(const float* __restrict__ inp, const float* __restrict__ g,
               const float* __restrict__ bsh, USHORT* __restrict__ out)
{
    const int tid = threadIdx.x;
    const size_t row = blockIdx.x;
    float4 t = ((const float4*)inp)[row * 256 + tid];
    float v[4] = { t.x, t.y, t.z, t.w };
    float s = v[0] + v[1] + v[2] + v[3];
    float sq = v[0]*v[0] + v[1]*v[1] + v[2]*v[2] + v[3]*v[3];
    #pragma unroll
    for (int off = 32; off; off >>= 1) { s += __shfl_down(s, off); sq += __shfl_down(sq, off); }
    __shared__ float red[8];
    const int wv = tid >> 6;
    if ((tid & 63) == 0) { red[wv] = s; red[wv + 4] = sq; }
    __syncthreads();
    const float S  = red[0] + red[1] + red[2] + red[3];
    const float SQ = red[4] + red[5] + red[6] + red[7];
    const float mu = S * (1.0f / 1024.0f);
    const float var = SQ * (1.0f / 1024.0f) - mu * mu;
    const float rs = rsqrtf(var + 1e-5f);
    float4 gv = ((const float4*)g)[tid];
    float4 bv = ((const float4*)bsh)[tid];
    ushort4 o;
    o.x = f2bf((v[0] - mu) * rs * gv.x + bv.x);
    o.y = f2bf((v[1] - mu) * rs * gv.y + bv.y);
    o.z = f2bf((v[2] - mu) * rs * gv.z + bv.z);
    o.w = f2bf((v[3] - mu) * rs * gv.w + bv.w);
    ((ushort4*)out)[row * 256 + tid] = o;
}

// ---------------- 128x128 GEMM (verified structure), kept for delta --------
// EPI 2: softplus(v + bias) -> f32 out (delta, single-pass K, no split-K)
template<int EPI>
__global__ __launch_bounds__(256)
void gemm_bt(const USHORT* __restrict__ A, const USHORT* __restrict__ B,
             const float* __restrict__ bias, void* __restrict__ outp,
             void* __restrict__ outp2, int M, int N, int K, int lda, int ldb)
{
    __shared__ __align__(16) unsigned char smem[32768];
    USHORT* As = (USHORT*)smem;
    USHORT* Bs = (USHORT*)(smem + 8192);
    const int tid = threadIdx.x;
    const int lane = tid & 63;
    const int w = tid >> 6;
    const int wr = w >> 1, wc = w & 1;

    const int nx = gridDim.x, ny = gridDim.y;
    const int pid = blockIdx.y * nx + blockIdx.x;
    const int npg = 8 * nx;
    const int gid = pid / npg;
    const int first = gid * 8;
    const int rem = ny - first;
    const int gsz = (rem < 8) ? rem : 8;
    const int py = first + (pid % npg) % gsz;
    const int px = (pid % npg) / gsz;
    const int tm = py * 128;
    const int tn = px * 128;

    f32x4 acc[4][4];
    #pragma unroll
    for (int i = 0; i < 4; i++)
        #pragma unroll
        for (int j = 0; j < 4; j++) acc[i][j] = (f32x4){0.f, 0.f, 0.f, 0.f};

    const int srow = tid >> 2;
    const int scol = (tid & 3) * 8;
    const USHORT* gA0 = A + (size_t)(tm + srow) * lda + scol;
    const USHORT* gA1 = A + (size_t)(tm + 64 + srow) * lda + scol;
    const USHORT* gB0 = B + (size_t)(tn + srow) * ldb + scol;
    const USHORT* gB1 = B + (size_t)(tn + 64 + srow) * ldb + scol;
    USHORT* lA0 = As + w * 512;
    USHORT* lA1 = As + 2048 + w * 512;
    USHORT* lB0 = Bs + w * 512;
    USHORT* lB1 = Bs + 2048 + w * 512;

    const int fr = lane & 15;
    const int fko = (lane >> 4) * 8;
    const int quad = lane >> 4;

    for (int k0 = 0; k0 < K; k0 += 64) {
        gload_lds16(gA0 + k0, lA0);
        gload_lds16(gA1 + k0, lA1);
        gload_lds16(gB0 + k0, lB0);
        gload_lds16(gB1 + k0, lB1);
        gload_lds16(gA0 + k0 + 32, lA0 + 8192);
        gload_lds16(gA1 + k0 + 32, lA1 + 8192);
        gload_lds16(gB0 + k0 + 32, lB0 + 8192);
        gload_lds16(gB1 + k0 + 32, lB1 + 8192);
        __syncthreads();
        #pragma unroll
        for (int h = 0; h < 2; h++) {
            const USHORT* Ah = As + h * 8192;
            const USHORT* Bh = Bs + h * 8192;
            bf16x8 af[4], bfr[4];
            #pragma unroll
            for (int i = 0; i < 4; i++) {
                af[i]  = *(const bf16x8*)(Ah + (wr * 64 + i * 16 + fr) * 32 + fko);
                bfr[i] = *(const bf16x8*)(Bh + (wc * 64 + i * 16 + fr) * 32 + fko);
            }
            #pragma unroll
            for (int i = 0; i < 4; i++)
                #pragma unroll
                for (int j = 0; j < 4; j++)
                    acc[i][j] = __builtin_amdgcn_mfma_f32_16x16x32_bf16(af[i], bfr[j], acc[i][j], 0, 0, 0);
        }
        __syncthreads();
    }

    float* eW = (float*)(smem + (size_t)w * 4352);
    const int rr = lane >> 5;
    const int cc = lane & 31;
    const int gcolb = tn + wc * 64;
    float2 bvv = *(const float2*)&bias[gcolb + cc * 2];

    #pragma unroll
    for (int i = 0; i < 4; i++) {
        #pragma unroll
        for (int j = 0; j < 4; j++)
            #pragma unroll
            for (int r = 0; r < 4; r++)
                eW[(quad * 4 + r) * 68 + j * 16 + fr] = acc[i][j][r];
        __syncthreads();
        const int grow0 = tm + wr * 64 + i * 16;
        #pragma unroll
        for (int rp = 0; rp < 8; rp++) {
            const int row = rp * 2 + rr;
            const float2 v = *(const float2*)&eW[row * 68 + cc * 2];
            const size_t gidx = (size_t)(grow0 + row) * N + gcolb + cc * 2;
            if constexpr (EPI == 2) {
                const float z0 = v.x + bvv.x, z1 = v.y + bvv.y;
                const float o0 = (z0 > 20.f) ? z0 : 0.69314718f * __log2f(1.f + fexp2(z0 * 1.44269504f));
                const float o1 = (z1 > 20.f) ? z1 : 0.69314718f * __log2f(1.f + fexp2(z1 * 1.44269504f));
                *(float2*)((float*)outp + gidx) = make_float2(o0, o1);
            }
        }
        __syncthreads();
    }
    (void)outp2; (void)M;
}

// ---------------- 256x256 GEMM, 8 waves, BK=32, ring-4 (R1 best: 43.2us) ----
// Reverted to the best-measured variant: stage 2 tiles ahead into 4-slot ring,
// vmcnt(4) boundary wait (never 0 mid-loop), ONE barrier per tile, compiler
// free to pipeline reads/MFMA (R2-R4 phase surgery all regressed).
template<int EPI>
__global__ __launch_bounds__(512)
void gemm256(const USHORT* __restrict__ A, const USHORT* __restrict__ B,
             const float* __restrict__ bias, void* __restrict__ outp,
             void* __restrict__ outp2, int M, int N, int K, int lda, int ldb)
{
    __shared__ __align__(16) unsigned char smem[131072];
    const int tid = threadIdx.x;
    const int lane = tid & 63;
    const int w = tid >> 6;          // 0..7
    const int wr = w >> 2;           // 0..1  (row half)
    const int wc = w & 3;            // 0..3  (col quarter)

    const int gx = gridDim.x;
    const int pid = blockIdx.y * gx + blockIdx.x;
    const int nwg = gx * gridDim.y;
    const int cpx = nwg >> 3;
    const int s = (pid & 7) * cpx + (pid >> 3);
    const int px = s % gx;
    const int py = s / gx;
    const int tm = py * 256;
    const int tn = px * 256;

    USHORT* po = nullptr;
    if constexpr (EPI == 3) {
        const int z = blockIdx.z;
        A += (size_t)z * K;
        B += (size_t)z * K;
        po = ((z < 2) ? (USHORT*)outp : (USHORT*)outp2) + (size_t)(z & 1) * ((size_t)M * N);
    }

    const int sr = tid >> 2;
    const int su = (tid & 3) ^ ((tid >> 3) & 3);
    const USHORT* gA0 = A + (size_t)(tm + sr) * lda + su * 8;
    const USHORT* gA1 = A + (size_t)(tm + 128 + sr) * lda + su * 8;
    const USHORT* gB0 = B + (size_t)(tn + sr) * ldb + su * 8;
    const USHORT* gB1 = B + (size_t)(tn + 128 + sr) * ldb + su * 8;

    const int fr = lane & 15;
    const int quad = lane >> 4;
    const int uR = quad ^ ((fr >> 1) & 3);
    const int loff = fr * 32 + uR * 8;

    f32x4 acc[8][4];
    #pragma unroll
    for (int i = 0; i < 8; i++)
        #pragma unroll
        for (int j = 0; j < 4; j++) acc[i][j] = (f32x4){0.f, 0.f, 0.f, 0.f};

    const int NT = K >> 5;           // BK=32

    auto stage = [&](int t) {
        unsigned char* sb = smem + (size_t)(t & 3) * 32768;
        const size_t koff = (size_t)t * 32;
        gload_lds16(gA0 + koff, sb + w * 1024);
        gload_lds16(gA1 + koff, sb + 8192 + w * 1024);
        gload_lds16(gB0 + koff, sb + 16384 + w * 1024);
        gload_lds16(gB1 + koff, sb + 24576 + w * 1024);
    };

    stage(0);
    stage(1);

    for (int t = 0; t < NT; ++t) {
        if (t + 1 < NT) asm volatile("s_waitcnt vmcnt(4)" ::: "memory");
        else            asm volatile("s_waitcnt vmcnt(0)" ::: "memory");
        __builtin_amdgcn_s_barrier();
        if (t + 2 < NT) stage(t + 2);

        const USHORT* sA = (const USHORT*)(smem + (size_t)(t & 3) * 32768);
        const USHORT* sB = sA + 8192;
        bf16x8 a[4], b[4];
        #pragma unroll
        for (int j = 0; j < 4; j++)
            b[j] = *(const bf16x8*)(sB + (wc * 64 + j * 16) * 32 + loff);
        #pragma unroll
        for (int i = 0; i < 4; i++)
            a[i] = *(const bf16x8*)(sA + (wr * 128 + i * 16) * 32 + loff);
        __builtin_amdgcn_s_setprio(1);
        #pragma unroll
        for (int i = 0; i < 4; i++)
            #pragma unroll
            for (int j = 0; j < 4; j++)
                acc[i][j] = __builtin_amdgcn_mfma_f32_16x16x32_bf16(a[i], b[j], acc[i][j], 0, 0, 0);
        __builtin_amdgcn_s_setprio(0);
        #pragma unroll
        for (int i = 0; i < 4; i++)
            a[i] = *(const bf16x8*)(sA + (wr * 128 + 64 + i * 16) * 32 + loff);
        __builtin_amdgcn_s_setprio(1);
        #pragma unroll
        for (int i = 0; i < 4; i++)
            #pragma unroll
            for (int j = 0; j < 4; j++)
                acc[4 + i][j] = __builtin_amdgcn_mfma_f32_16x16x32_bf16(a[i], b[j], acc[4 + i][j], 0, 0, 0);
        __builtin_amdgcn_s_setprio(0);
    }

    // epilogue: per-wave private 16x68 f32 LDS slice (bytes [0,34816) = ring
    // slots 0/1; last tile read slot 3 -> no cross-wave hazard, no barrier.
    float* eW = (float*)(smem + (size_t)w * 4352);
    const int erow = lane >> 2;
    const int ecq = lane & 3;
    const int gcolb = tn + wc * 64 + ecq * 16;
    float bb[16];
    if constexpr (EPI == 1) {
        #pragma unroll
        for (int q = 0; q < 4; q++) {
            float4 bv = *(const float4*)&bias[gcolb + q * 4];
            bb[q*4+0] = bv.x; bb[q*4+1] = bv.y; bb[q*4+2] = bv.z; bb[q*4+3] = bv.w;
        }
    }
    #pragma unroll
    for (int i = 0; i < 8; i++) {
        #pragma unroll
        for (int j = 0; j < 4; j++)
            #pragma unroll
            for (int r = 0; r < 4; r++)
                eW[(quad * 4 + r) * 68 + j * 16 + fr] = acc[i][j][r];
        float v[16];
        #pragma unroll
        for (int q = 0; q < 4; q++) {
            float4 t4 = *(const float4*)&eW[erow * 68 + ecq * 16 + q * 4];
            v[q*4+0] = t4.x; v[q*4+1] = t4.y; v[q*4+2] = t4.z; v[q*4+3] = t4.w;
        }
        const int grow = tm + wr * 128 + i * 16 + erow;
        uint32_t pk[8];
        if constexpr (EPI == 1) {
            #pragma unroll
            for (int q = 0; q < 8; q++) {
                const float z0 = v[2*q]   + bb[2*q];
                const float z1 = v[2*q+1] + bb[2*q+1];
                const float u0 = z0 * (0.7978845608f + 0.035677408f * z0 * z0);
                const float u1 = z1 * (0.7978845608f + 0.035677408f * z1 * z1);
                const float s0 = __builtin_amdgcn_rcpf(1.f + fexp2(2.885390082f * u0));
                const float s1 = __builtin_amdgcn_rcpf(1.f + fexp2(2.885390082f * u1));
                const float g0 = z0 * (1.f - s0), g1 = z1 * (1.f - s1);
                pk[q] = (uint32_t)f2bf(g0) | ((uint32_t)f2bf(g1) << 16);
            }
            USHORT* op = (USHORT*)outp + (size_t)grow * N + gcolb;
            *(uint4*)op = make_uint4(pk[0], pk[1], pk[2], pk[3]);
            *(uint4*)(op + 8) = make_uint4(pk[4], pk[5], pk[6], pk[7]);
        } else {
            #pragma unroll
            for (int q = 0; q < 8; q++)
                pk[q] = (uint32_t)f2bf(v[2*q]) | ((uint32_t)f2bf(v[2*q+1]) << 16);
            USHORT* op = po + (size_t)grow * N + gcolb;
            *(uint4*)op = make_uint4(pk[0], pk[1], pk[2], pk[3]);
            *(uint4*)(op + 8) = make_uint4(pk[4], pk[5], pk[6], pk[7]);
        }
    }
}

// ---------------- NEW: 128x256 GEMM, BK=32, ring-3 LDS 72KB -> 2 blocks/CU --
// A/B probe vs gemm256: same verified swizzle/read formulas, but LDS sized so
// TWO blocks co-reside per CU (16 waves/CU): inter-block slip supplies the
// MFMA<->LDS overlap that barrier-locked 1-block/CU schedules never achieved
// (MfmaUtil pinned at 29% across R1-R4).  8 waves 2Mx4N, per-wave 64x64
// (acc[4][4] = 64 VGPR).  3 gloads/tile, staged 2 tiles ahead, vmcnt(6).
// EPI 3: raw bf16 partial (split-K via blockIdx.z).  EPI 1: gelu -> bf16.
template<int EPI>
__global__ __launch_bounds__(512)
void gemm_tlp(const USHORT* __restrict__ A, const USHORT* __restrict__ B,
              const float* __restrict__ bias, void* __restrict__ outp,
              void* __restrict__ outp2, int M, int N, int K, int lda, int ldb)
{
    __shared__ __align__(16) unsigned char smem[73728];   // 3 x 24KB ring
    const int tid = threadIdx.x;
    const int lane = tid & 63;
    const int w = tid >> 6;          // 0..7
    const int wr = w >> 2;           // 0..1  (M half of 128)
    const int wc = w & 3;            // 0..3  (N quarter of 256)

    // T1: bijective XCD swizzle (gridDim.x = M-tiles, gridDim.y = N-tiles)
    const int gx = gridDim.x;
    const int pid = blockIdx.y * gx + blockIdx.x;
    const int nwg = gx * gridDim.y;
    const int cpx = nwg >> 3;
    const int sw = (pid & 7) * cpx + (pid >> 3);
    const int tm = (sw % gx) * 128;
    const int tn = (sw / gx) * 256;

    USHORT* po = nullptr;
    if constexpr (EPI == 3) {
        const int z = blockIdx.z;
        A += (size_t)z * K;
        B += (size_t)z * K;
        po = ((z < 2) ? (USHORT*)outp : (USHORT*)outp2) + (size_t)(z & 1) * ((size_t)M * N);
    }

    // staging: rows of 32 elems (64B).  Thread -> row tid>>2, unit tid&3;
    // source fetches unit (tid&3)^((row>>1)&3) so linear LDS is swizzled.
    const int srow = tid >> 2;                       // 0..127
    const int su = (tid & 3) ^ ((tid >> 3) & 3);
    const USHORT* gA  = A + (size_t)(tm + srow) * lda + su * 8;
    const USHORT* gB0 = B + (size_t)(tn + srow) * ldb + su * 8;
    const USHORT* gB1 = B + (size_t)(tn + 128 + srow) * ldb + su * 8;

    // fragment read: row r, logical unit quad -> phys unit quad^((r>>1)&3)
    const int fr = lane & 15;
    const int quad = lane >> 4;
    const int uR = quad ^ ((fr >> 1) & 3);
    const int loff = fr * 32 + uR * 8;

    f32x4 acc[4][4];
    #pragma unroll
    for (int i = 0; i < 4; i++)
        #pragma unroll
        for (int j = 0; j < 4; j++) acc[i][j] = (f32x4){0.f, 0.f, 0.f, 0.f};

    const int NT = K >> 5;           // BK=32

    auto stage = [&](int t) {        // A 8KB + B 16KB = 3 gloads/thread
        unsigned char* sb = smem + (size_t)(t % 3) * 24576;
        const size_t ko = (size_t)t * 32;
        gload_lds16(gA  + ko, sb +         w * 1024);   // A rows 0..127
        gload_lds16(gB0 + ko, sb +  8192 + w * 1024);   // B rows 0..127
        gload_lds16(gB1 + ko, sb + 16384 + w * 1024);   // B rows 128..255
    };

    stage(0);
    stage(1);

    for (int t = 0; t < NT; ++t) {
        if (t + 2 < NT) { stage(t + 2); asm volatile("s_waitcnt vmcnt(6)" ::: "memory"); }
        else if (t + 1 < NT) asm volatile("s_waitcnt vmcnt(3)" ::: "memory");
        else                 asm volatile("s_waitcnt vmcnt(0)" ::: "memory");
        __builtin_amdgcn_s_barrier();

        const USHORT* sA = (const USHORT*)(smem + (size_t)(t % 3) * 24576);
        const USHORT* sB = sA + 4096;        // +8KB (elems)
        bf16x8 a[4], b[4];
        #pragma unroll
        for (int j = 0; j < 4; j++)
            b[j] = *(const bf16x8*)(sB + (wc * 64 + j * 16) * 32 + loff);
        #pragma unroll
        for (int i = 0; i < 4; i++)
            a[i] = *(const bf16x8*)(sA + (wr * 64 + i * 16) * 32 + loff);
        __builtin_amdgcn_s_setprio(1);
        #pragma unroll
        for (int i = 0; i < 4; i++)
            #pragma unroll
            for (int j = 0; j < 4; j++)
                acc[i][j] = __builtin_amdgcn_mfma_f32_16x16x32_bf16(a[i], b[j], acc[i][j], 0, 0, 0);
        __builtin_amdgcn_s_setprio(0);
        __builtin_amdgcn_s_barrier();
    }

    // epilogue: eW slices overlap ring slots -> barrier first.
    __syncthreads();
    float* eW = (float*)(smem + (size_t)w * 4352);
    const int erow = lane >> 2;
    const int ecq = lane & 3;
    const int gcolb = tn + wc * 64 + ecq * 16;
    float bb[16];
    if constexpr (EPI == 1) {
        #pragma unroll
        for (int q = 0; q < 4; q++) {
            float4 bv = *(const float4*)&bias[gcolb + q * 4];
            bb[q*4+0] = bv.x; bb[q*4+1] = bv.y; bb[q*4+2] = bv.z; bb[q*4+3] = bv.w;
        }
    }
    #pragma unroll
    for (int i = 0; i < 4; i++) {
        #pragma unroll
        for (int j = 0; j < 4; j++)
            #pragma unroll
            for (int r = 0; r < 4; r++)
                eW[(quad * 4 + r) * 68 + j * 16 + fr] = acc[i][j][r];
        float v[16];
        #pragma unroll
        for (int q = 0; q < 4; q++) {
            float4 t4 = *(const float4*)&eW[erow * 68 + ecq * 16 + q * 4];
            v[q*4+0] = t4.x; v[q*4+1] = t4.y; v[q*4+2] = t4.z; v[q*4+3] = t4.w;
        }
        const int grow = tm + wr * 64 + i * 16 + erow;
        uint32_t pk[8];
        if constexpr (EPI == 1) {
            #pragma unroll
            for (int q = 0; q < 8; q++) {
                const float z0 = v[2*q]   + bb[2*q];
                const float z1 = v[2*q+1] + bb[2*q+1];
                const float u0 = z0 * (0.7978845608f + 0.035677408f * z0 * z0);
                const float u1 = z1 * (0.7978845608f + 0.035677408f * z1 * z1);
                const float s0 = __builtin_amdgcn_rcpf(1.f + fexp2(2.885390082f * u0));
                const float s1 = __builtin_amdgcn_rcpf(1.f + fexp2(2.885390082f * u1));
                const float g0 = z0 * (1.f - s0), g1 = z1 * (1.f - s1);
                pk[q] = (uint32_t)f2bf(g0) | ((uint32_t)f2bf(g1) << 16);
            }
            USHORT* op = (USHORT*)outp + (size_t)grow * N + gcolb;
            *(uint4*)op = make_uint4(pk[0], pk[1], pk[2], pk[3]);
            *(uint4*)(op + 8) = make_uint4(pk[4], pk[5], pk[6], pk[7]);
        } else {
            #pragma unroll
            for (int q = 0; q < 8; q++)
                pk[q] = (uint32_t)f2bf(v[2*q]) | ((uint32_t)f2bf(v[2*q+1]) << 16);
            USHORT* op = po + (size_t)grow * N + gcolb;
            *(uint4*)op = make_uint4(pk[0], pk[1], pk[2], pk[3]);
            *(uint4*)(op + 8) = make_uint4(pk[4], pk[5], pk[6], pk[7]);
        }
    }
    (void)bias;
}

// ---------------- FFN2 split-K reduce: out = sum(partials) + bias + extra ---
__global__ __launch_bounds__(256)
void ffn2_reduce(const USHORT* __restrict__ p01, const USHORT* __restrict__ p23,
                 const float* __restrict__ bias, const float* __restrict__ extra,
                 float* __restrict__ out)
{
    const size_t PS = (size_t)4096 * 1024;
    const size_t i = ((size_t)blockIdx.x * 256 + threadIdx.x) * 4;
    ushort4 a = *(const ushort4*)(p01 + i);
    ushort4 b = *(const ushort4*)(p01 + PS + i);
    ushort4 c = *(const ushort4*)(p23 + i);
    ushort4 d = *(const ushort4*)(p23 + PS + i);
    float4 bv = *(const float4*)(bias + (i & 1023));
    float4 ev = *(const float4*)(extra + i);
    float4 o;
    o.x = b2f(a.x) + b2f(b.x) + b2f(c.x) + b2f(d.x) + bv.x + ev.x;
    o.y = b2f(a.y) + b2f(b.y) + b2f(c.y) + b2f(d.y) + bv.y + ev.y;
    o.z = b2f(a.z) + b2f(b.z) + b2f(c.z) + b2f(d.z) + bv.z + ev.z;
    o.w = b2f(a.w) + b2f(b.w) + b2f(c.w) + b2f(d.w) + bv.w + ev.w;
    *(float4*)(out + i) = o;
}

// ---------------- bc = xn @ Wbc^T + bbc via MFMA: 64 tokens/block ----------
__global__ __launch_bounds__(256)
void bc_mfma(const USHORT* __restrict__ xn, const USHORT* __restrict__ WbcB,
             const float* __restrict__ bbc, float* __restrict__ bc)
{
    __shared__ __align__(16) USHORT As[64 * 32];
    __shared__ __align__(16) USHORT Bs[32 * 32];
    const int tid = threadIdx.x;
    const int lane = tid & 63;
    const int w = tid >> 6;
    const int tok0 = blockIdx.x * 64;

    const int srow = tid >> 2;
    const int scol = (tid & 3) * 8;
    const USHORT* gA = xn + (size_t)(tok0 + srow) * 1024 + scol;
    const USHORT* gB = WbcB + (size_t)srow * 1024 + scol;
    USHORT* lA = As + w * 512;
    USHORT* lB = Bs + w * 512;

    const int fr = lane & 15;
    const int fko = (lane >> 4) * 8;
    const int quad = lane >> 4;

    f32x4 acc[2];
    acc[0] = (f32x4){0.f, 0.f, 0.f, 0.f};
    acc[1] = (f32x4){0.f, 0.f, 0.f, 0.f};

    for (int k0 = 0; k0 < 1024; k0 += 32) {
        gload_lds16(gA + k0, lA);
        if (w < 2) gload_lds16(gB + k0, lB);
        __syncthreads();
        bf16x8 af = *(const bf16x8*)(As + (w * 16 + fr) * 32 + fko);
        bf16x8 b0 = *(const bf16x8*)(Bs + (fr) * 32 + fko);
        bf16x8 b1 = *(const bf16x8*)(Bs + (16 + fr) * 32 + fko);
        acc[0] = __builtin_amdgcn_mfma_f32_16x16x32_bf16(af, b0, acc[0], 0, 0, 0);
        acc[1] = __builtin_amdgcn_mfma_f32_16x16x32_bf16(af, b1, acc[1], 0, 0, 0);
        __syncthreads();
    }

    #pragma unroll
    for (int j = 0; j < 2; j++) {
        const int col = j * 16 + fr;
        const float bv = bbc[col];
        #pragma unroll
        for (int r = 0; r < 4; r++) {
            const int row = tok0 + w * 16 + quad * 4 + r;
            bc[(size_t)row * 32 + col] = acc[j][r] + bv;
        }
    }
}

// ---------------- selective scan v3: chunked parallel, lane=h, n in regs ----
#define SCAN_P 64
#define SCAN_T 32

__global__ __launch_bounds__(256)
void scan_pass1(const USHORT* __restrict__ xn, const float* __restrict__ delta,
                const float* __restrict__ bc, const float* __restrict__ Alog,
                float* __restrict__ sEnd, float* __restrict__ Ptot)
{
    const int tid = threadIdx.x;
    const int h = blockIdx.x * 256 + tid;
    const int b = blockIdx.y;
    const int p = blockIdx.z;
    const size_t tok0 = (size_t)b * 2048 + p * SCAN_T;

    __shared__ __align__(16) float sBC[SCAN_T][32];
    {
        int t = tid >> 3, q = (tid & 7) * 4;
        *(float4*)&sBC[t][q] = *(const float4*)(bc + (tok0 + t) * 32 + q);
    }

    float en[16], s[16], P[16];
    #pragma unroll
    for (int k = 0; k < 4; k++) {
        float4 a = *(const float4*)(Alog + h * 16 + k * 4);
        en[k*4+0] = -__expf(a.x) * 1.44269504f;
        en[k*4+1] = -__expf(a.y) * 1.44269504f;
        en[k*4+2] = -__expf(a.z) * 1.44269504f;
        en[k*4+3] = -__expf(a.w) * 1.44269504f;
    }
    #pragma unroll
    for (int n = 0; n < 16; n++) { s[n] = 0.f; P[n] = 1.f; }
    __syncthreads();

    const float* dp = delta + tok0 * 1024 + h;
    const USHORT* xp = xn + tok0 * 1024 + h;
    float d_c = dp[0];
    USHORT x_c = xp[0];
    for (int t = 0; t < SCAN_T; ++t) {
        const int tn = (t < SCAN_T - 1) ? t + 1 : t;
        float d_n = dp[(size_t)tn * 1024];
        USHORT x_n = xp[(size_t)tn * 1024];
        const float dx = d_c * b2f(x_c);
        #pragma unroll
        for (int k = 0; k < 4; k++) {
            float4 Bv = *(const float4*)&sBC[t][k*4];
            float bb[4] = { Bv.x, Bv.y, Bv.z, Bv.w };
            #pragma unroll
            for (int j = 0; j < 4; j++) {
                const int n = k*4 + j;
                const float dA = fexp2(d_c * en[n]);
                s[n] = fmaf(dA, s[n], dx * bb[j]);
                P[n] *= dA;
            }
        }
        d_c = d_n; x_c = x_n;
    }

    const size_t off = (size_t)p * 32768 + ((size_t)b * 1024 + h) * 16;
    #pragma unroll
    for (int k = 0; k < 4; k++) {
        *(float4*)(sEnd + off + k*4) = (float4){ s[k*4], s[k*4+1], s[k*4+2], s[k*4+3] };
        *(float4*)(Ptot + off + k*4) = (float4){ P[k*4], P[k*4+1], P[k*4+2], P[k*4+3] };
    }
}

__global__ __launch_bounds__(256)
void scan_mid(const float* __restrict__ sEnd, const float* __restrict__ Ptot,
              float* __restrict__ sIn)
{
    const int L = blockIdx.x * 256 + threadIdx.x;
    float s = 0.f;
    #pragma unroll 8
    for (int p = 0; p < SCAN_P; ++p) {
        const size_t off = (size_t)p * 32768 + L;
        sIn[off] = s;
        s = fmaf(Ptot[off], s, sEnd[off]);
    }
}

__global__ __launch_bounds__(256)
void scan_pass2(const float* __restrict__ x, const USHORT* __restrict__ xn,
                const float* __restrict__ delta, const float* __restrict__ bc,
                const float* __restrict__ Alog, const float* __restrict__ Dp,
                const float* __restrict__ sIn, float* __restrict__ ssm)
{
    const int tid = threadIdx.x;
    const int h = blockIdx.x * 256 + tid;
    const int b = blockIdx.y;
    const int p = blockIdx.z;
    const size_t tok0 = (size_t)b * 2048 + p * SCAN_T;

    __shared__ __align__(16) float sBC[SCAN_T][32];
    {
        int t = tid >> 3, q = (tid & 7) * 4;
        *(float4*)&sBC[t][q] = *(const float4*)(bc + (tok0 + t) * 32 + q);
    }

    float en[16], s[16];
    #pragma unroll
    for (int k = 0; k < 4; k++) {
        float4 a = *(const float4*)(Alog + h * 16 + k * 4);
        en[k*4+0] = -__expf(a.x) * 1.44269504f;
        en[k*4+1] = -__expf(a.y) * 1.44269504f;
        en[k*4+2] = -__expf(a.z) * 1.44269504f;
        en[k*4+3] = -__expf(a.w) * 1.44269504f;
    }
    const size_t off = (size_t)p * 32768 + ((size_t)b * 1024 + h) * 16;
    #pragma unroll
    for (int k = 0; k < 4; k++) {
        float4 v = *(const float4*)(sIn + off + k*4);
        s[k*4] = v.x; s[k*4+1] = v.y; s[k*4+2] = v.z; s[k*4+3] = v.w;
    }
    const float Dv = Dp[h];
    __syncthreads();

    const float* dp = delta + tok0 * 1024 + h;
    const USHORT* xp = xn + tok0 * 1024 + h;
    const float* xrp = x + tok0 * 1024 + h;
    float* op = ssm + tok0 * 1024 + h;

    float d_c = dp[0];
    USHORT x_c = xp[0];
    float xr_c = xrp[0];
    for (int t = 0; t < SCAN_T; ++t) {
        const int tn = (t < SCAN_T - 1) ? t + 1 : t;
        float d_n = dp[(size_t)tn * 1024];
        USHORT x_n = xp[(size_t)tn * 1024];
        float xr_n = xrp[(size_t)tn * 1024];
        const float xv = b2f(x_c);
        const float dx = d_c * xv;
        float y = 0.f;
        #pragma unroll
        for (int k = 0; k < 4; k++) {
            float4 Bv = *(const float4*)&sBC[t][k*4];
            float4 Cv = *(const float4*)&sBC[t][16 + k*4];
            float bb[4] = { Bv.x, Bv.y, Bv.z, Bv.w };
            float cc[4] = { Cv.x, Cv.y, Cv.z, Cv.w };
            #pragma unroll
            for (int j = 0; j < 4; j++) {
                const int n = k*4 + j;
                const float dA = fexp2(d_c * en[n]);
                s[n] = fmaf(dA, s[n], dx * bb[j]);
                y = fmaf(cc[j], s[n], y);
            }
        }
        op[(size_t)t * 1024] = xr_c + y + Dv * xv;
        d_c = d_n; x_c = x_n; xr_c = xr_n;
    }
}

extern "C" void kernel_launch(void* const* d_in, const int* in_sizes, int n_in,
                              void* d_out, int out_size, void* d_ws, size_t ws_size,
                              hipStream_t stream)
{
    const float* x    = (const float*)d_in[0];
    const float* ln1g = (const float*)d_in[1];
    const float* ln1b = (const float*)d_in[2];
    const float* Wd   = (const float*)d_in[3];
    const float* bd   = (const float*)d_in[4];
    const float* Wbc  = (const float*)d_in[5];
    const float* bbc  = (const float*)d_in[6];
    const float* Alog = (const float*)d_in[7];
    const float* Dp   = (const float*)d_in[8];
    const float* ln2g = (const float*)d_in[9];
    const float* ln2b = (const float*)d_in[10];
    const float* W1   = (const float*)d_in[11];
    const float* b1   = (const float*)d_in[12];
    const float* W2   = (const float*)d_in[13];
    const float* b2   = (const float*)d_in[14];
    float* out = (float*)d_out;

    char* ws = (char*)d_ws;
    const size_t MB = 1024 * 1024;
    float*  deltaW = (float*)(ws + 0);            // 16 MiB (4096x1024 f32)
    float*  ssmW   = (float*)(ws + 16 * MB);      // 16 MiB (4096x1024 f32)
    USHORT* xnW    = (USHORT*)(ws + 32 * MB);     //  8 MiB (4096x1024 bf16)
    USHORT* nrmW   = (USHORT*)(ws + 40 * MB);     //  8 MiB (4096x1024 bf16)
    USHORT* hffW   = (USHORT*)(ws + 48 * MB);     // 32 MiB (4096x4096 bf16)
    float*  bcW    = (float*)(ws + 80 * MB);      // 512 KiB (4096x32 f32)
    USHORT* WdB    = (USHORT*)(ws + 81 * MB);     //  2 MiB (1024x1024 bf16)
    USHORT* W1B    = (USHORT*)(ws + 83 * MB);     //  8 MiB (4096x1024 bf16)
    USHORT* W2B    = (USHORT*)(ws + 91 * MB);     //  8 MiB (1024x4096 bf16)
    USHORT* WbcB   = (USHORT*)(ws + 99 * MB);     // 64 KiB (32x1024 bf16)
    // scan scratch aliases hffW (dead until FFN1): 3 x 8 MiB
    float*  sEndW  = (float*)(ws + 48 * MB);
    float*  PtotW  = (float*)(ws + 56 * MB);
    float*  sInW   = (float*)(ws + 64 * MB);
    // FFN2 split-K partials alias deltaW (splits 0,1) and xnW/nrmW (2,3)
    USHORT* ffn2p01 = (USHORT*)(ws + 0);          // 16 MiB: 2 x 4096x1024 bf16
    USHORT* ffn2p23 = (USHORT*)(ws + 32 * MB);    // 16 MiB: 2 x 4096x1024 bf16

    // 0. convert weights f32 -> bf16
    f2b_kernel<<<1024, 256, 0, stream>>>(Wd, WdB, 1024 * 1024);
    f2b_kernel<<<4096, 256, 0, stream>>>(W1, W1B, 4096 * 1024);
    f2b_kernel<<<4096, 256, 0, stream>>>(W2, W2B, 1024 * 4096);
    f2b_kernel<<<32, 256, 0, stream>>>(Wbc, WbcB, 32 * 1024);
    // 1. xn = LN1(x)                         (bf16)
    ln_kernel<<<4096, 256, 0, stream>>>(x, ln1g, ln1b, xnW);
    // 2. delta = softplus(xn @ Wd^T + bd)    (f32), fused epilogue
    gemm_bt<2><<<dim3(8, 32), 256, 0, stream>>>(xnW, WdB, bd, deltaW, nullptr, 4096, 1024, 1024, 1024, 1024);
    // 3. bc = xn @ Wbc^T + bbc               (f32), MFMA micro-GEMM
    bc_mfma<<<64, 256, 0, stream>>>(xnW, WbcB, bbc, bcW);
    // 4. ssm_out = x + scan(...) + D*xn      (f32), chunked parallel scan
    scan_pass1<<<dim3(4, 2, SCAN_P), 256, 0, stream>>>(xnW, deltaW, bcW, Alog, sEndW, PtotW);
    scan_mid<<<128, 256, 0, stream>>>(sEndW, PtotW, sInW);
    scan_pass2<<<dim3(4, 2, SCAN_P), 256, 0, stream>>>(x, xnW, deltaW, bcW, Alog, Dp, sInW, ssmW);
    // 5. normed = LN2(ssm_out)               (bf16)
    ln_kernel<<<4096, 256, 0, stream>>>(ssmW, ln2g, ln2b, nrmW);
    // 6. hff = gelu(normed @ W1^T + b1)      (bf16), gemm256 R1-best (A arm)
    gemm256<1><<<dim3(16, 16), 512, 0, stream>>>(nrmW, W1B, b1, hffW, nullptr, 4096, 4096, 1024, 1024, 1024);
    // 7a. FFN2 split-K=4 partials            (bf16), NEW 2-blocks/CU (B arm)
    gemm_tlp<3><<<dim3(32, 4, 4), 512, 0, stream>>>(hffW, W2B, nullptr, ffn2p01, ffn2p23, 4096, 1024, 1024, 4096, 4096);
    // 7b. out = sum(partials) + b2 + ssm_out (f32)
    ffn2_reduce<<<4096, 256, 0, stream>>>(ffn2p01, ffn2p23, b2, ssmW, out);

    (void)in_sizes; (void)n_in; (void)out_size; (void)ws_size;
}

// Round 6
// 293.464 us; speedup vs baseline: 1.0744x; 1.0744x over previous
//
#include <hip/hip_runtime.h>
#include <cstdint>
#include <cstddef>

typedef unsigned short USHORT;
typedef __bf16 bf16x8 __attribute__((ext_vector_type(8)));
typedef float f32x4 __attribute__((ext_vector_type(4)));

__device__ __forceinline__ float b2f(USHORT u) {
    union { unsigned int i; float f; } v; v.i = ((unsigned int)u) << 16; return v.f;
}
__device__ __forceinline__ USHORT f2bf(float f) {
    union { float f; unsigned int i; } v; v.f = f;
    unsigned int u = v.i;
    unsigned int r = (u + 0x7FFFu + ((u >> 16) & 1u)) >> 16;
    return (USHORT)r;
}
__device__ __forceinline__ float fexp2(float x) { return __builtin_amdgcn_exp2f(x); }

__device__ __forceinline__ void gload_lds16(const void* g, void* l) {
    __builtin_amdgcn_global_load_lds(
        (const __attribute__((address_space(1))) void*)(uintptr_t)g,
        (__attribute__((address_space(3))) void*)(uint32_t)(uintptr_t)l,
        16, 0, 0);
}

// ---------------- fused f32 -> bf16 conversion for ALL weights --------------
// unit = 4 elems.  Ranges (units): Wd [0,262144) W1 [262144,1310720)
// W2 [1310720,2359296) Wbc [2359296,2367488).  grid 9248 x 256 exact.
__global__ __launch_bounds__(256)
void f2b_all(const float* __restrict__ Wd, const float* __restrict__ W1,
             const float* __restrict__ W2, const float* __restrict__ Wbc,
             USHORT* __restrict__ WdB, USHORT* __restrict__ W1B,
             USHORT* __restrict__ W2B, USHORT* __restrict__ WbcB)
{
    const size_t u = (size_t)blockIdx.x * 256 + threadIdx.x;
    const float* src; USHORT* dst; size_t base;
    if (u < 262144)       { src = Wd;  dst = WdB;  base = 0; }
    else if (u < 1310720) { src = W1;  dst = W1B;  base = 262144; }
    else if (u < 2359296) { src = W2;  dst = W2B;  base = 1310720; }
    else                  { src = Wbc; dst = WbcB; base = 2359296; }
    const size_t i = (u - base) * 4;
    float4 v = *(const float4*)(src + i);
    ushort4 o;
    o.x = f2bf(v.x); o.y = f2bf(v.y); o.z = f2bf(v.z); o.w = f2bf(v.w);
    *(ushort4*)(dst + i) = o;
}

// ---------------- LayerNorm: wave-per-token (4 tokens/block, no barriers) ---
__global__ __launch_bounds__(256)
void ln_kernel(const float* __restrict__ inp, const float* __restrict__ g,
               const float* __restrict__ bsh, USHORT* __restrict__ out)
{
    const int tid = threadIdx.x;
    const int lane = tid & 63;
    const size_t row = (size_t)blockIdx.x * 4 + (tid >> 6);
    const float4* ip = (const float4*)inp + row * 256;
    float4 v[4];
    float s = 0.f, sq = 0.f;
    #pragma unroll
    for (int q = 0; q < 4; q++) {
        v[q] = ip[lane + 64 * q];
        s  += v[q].x + v[q].y + v[q].z + v[q].w;
        sq += v[q].x*v[q].x + v[q].y*v[q].y + v[q].z*v[q].z + v[q].w*v[q].w;
    }
    #pragma unroll
    for (int off = 32; off; off >>= 1) { s += __shfl_xor(s, off); sq += __shfl_xor(sq, off); }
    const float mu = s * (1.0f / 1024.0f);
    const float var = sq * (1.0f / 1024.0f) - mu * mu;
    const float rs = rsqrtf(var + 1e-5f);
    ushort4* op = (ushort4*)out + row * 256;
    #pragma unroll
    for (int q = 0; q < 4; q++) {
        float4 gv = ((const float4*)g)[lane + 64 * q];
        float4 bv = ((const float4*)bsh)[lane + 64 * q];
        ushort4 o;
        o.x = f2bf((v[q].x - mu) * rs * gv.x + bv.x);
        o.y = f2bf((v[q].y - mu) * rs * gv.y + bv.y);
        o.z = f2bf((v[q].z - mu) * rs * gv.z + bv.z);
        o.w = f2bf((v[q].w - mu) * rs * gv.w + bv.w);
        op[lane + 64 * q] = o;
    }
}

// ---------------- 128x128 GEMM (verified structure), kept for delta --------
// EPI 2: softplus(v + bias) -> f32 out (delta, single-pass K, no split-K)
template<int EPI>
__global__ __launch_bounds__(256)
void gemm_bt(const USHORT* __restrict__ A, const USHORT* __restrict__ B,
             const float* __restrict__ bias, void* __restrict__ outp,
             void* __restrict__ outp2, int M, int N, int K, int lda, int ldb)
{
    __shared__ __align__(16) unsigned char smem[32768];
    USHORT* As = (USHORT*)smem;
    USHORT* Bs = (USHORT*)(smem + 8192);
    const int tid = threadIdx.x;
    const int lane = tid & 63;
    const int w = tid >> 6;
    const int wr = w >> 1, wc = w & 1;

    const int nx = gridDim.x, ny = gridDim.y;
    const int pid = blockIdx.y * nx + blockIdx.x;
    const int npg = 8 * nx;
    const int gid = pid / npg;
    const int first = gid * 8;
    const int rem = ny - first;
    const int gsz = (rem < 8) ? rem : 8;
    const int py = first + (pid % npg) % gsz;
    const int px = (pid % npg) / gsz;
    const int tm = py * 128;
    const int tn = px * 128;

    f32x4 acc[4][4];
    #pragma unroll
    for (int i = 0; i < 4; i++)
        #pragma unroll
        for (int j = 0; j < 4; j++) acc[i][j] = (f32x4){0.f, 0.f, 0.f, 0.f};

    const int srow = tid >> 2;
    const int scol = (tid & 3) * 8;
    const USHORT* gA0 = A + (size_t)(tm + srow) * lda + scol;
    const USHORT* gA1 = A + (size_t)(tm + 64 + srow) * lda + scol;
    const USHORT* gB0 = B + (size_t)(tn + srow) * ldb + scol;
    const USHORT* gB1 = B + (size_t)(tn + 64 + srow) * ldb + scol;
    USHORT* lA0 = As + w * 512;
    USHORT* lA1 = As + 2048 + w * 512;
    USHORT* lB0 = Bs + w * 512;
    USHORT* lB1 = Bs + 2048 + w * 512;

    const int fr = lane & 15;
    const int fko = (lane >> 4) * 8;
    const int quad = lane >> 4;

    for (int k0 = 0; k0 < K; k0 += 64) {
        gload_lds16(gA0 + k0, lA0);
        gload_lds16(gA1 + k0, lA1);
        gload_lds16(gB0 + k0, lB0);
        gload_lds16(gB1 + k0, lB1);
        gload_lds16(gA0 + k0 + 32, lA0 + 8192);
        gload_lds16(gA1 + k0 + 32, lA1 + 8192);
        gload_lds16(gB0 + k0 + 32, lB0 + 8192);
        gload_lds16(gB1 + k0 + 32, lB1 + 8192);
        __syncthreads();
        #pragma unroll
        for (int h = 0; h < 2; h++) {
            const USHORT* Ah = As + h * 8192;
            const USHORT* Bh = Bs + h * 8192;
            bf16x8 af[4], bfr[4];
            #pragma unroll
            for (int i = 0; i < 4; i++) {
                af[i]  = *(const bf16x8*)(Ah + (wr * 64 + i * 16 + fr) * 32 + fko);
                bfr[i] = *(const bf16x8*)(Bh + (wc * 64 + i * 16 + fr) * 32 + fko);
            }
            #pragma unroll
            for (int i = 0; i < 4; i++)
                #pragma unroll
                for (int j = 0; j < 4; j++)
                    acc[i][j] = __builtin_amdgcn_mfma_f32_16x16x32_bf16(af[i], bfr[j], acc[i][j], 0, 0, 0);
        }
        __syncthreads();
    }

    float* eW = (float*)(smem + (size_t)w * 4352);
    const int rr = lane >> 5;
    const int cc = lane & 31;
    const int gcolb = tn + wc * 64;
    float2 bvv = *(const float2*)&bias[gcolb + cc * 2];

    #pragma unroll
    for (int i = 0; i < 4; i++) {
        #pragma unroll
        for (int j = 0; j < 4; j++)
            #pragma unroll
            for (int r = 0; r < 4; r++)
                eW[(quad * 4 + r) * 68 + j * 16 + fr] = acc[i][j][r];
        __syncthreads();
        const int grow0 = tm + wr * 64 + i * 16;
        #pragma unroll
        for (int rp = 0; rp < 8; rp++) {
            const int row = rp * 2 + rr;
            const float2 v = *(const float2*)&eW[row * 68 + cc * 2];
            const size_t gidx = (size_t)(grow0 + row) * N + gcolb + cc * 2;
            if constexpr (EPI == 2) {
                const float z0 = v.x + bvv.x, z1 = v.y + bvv.y;
                const float o0 = (z0 > 20.f) ? z0 : 0.69314718f * __log2f(1.f + fexp2(z0 * 1.44269504f));
                const float o1 = (z1 > 20.f) ? z1 : 0.69314718f * __log2f(1.f + fexp2(z1 * 1.44269504f));
                *(float2*)((float*)outp + gidx) = make_float2(o0, o1);
            }
        }
        __syncthreads();
    }
    (void)outp2; (void)M;
}

// ---------------- 256x256 GEMM, 8 waves, BK=32, ring-4 (R1 best) -----------
template<int EPI>
__global__ __launch_bounds__(512)
void gemm256(const USHORT* __restrict__ A, const USHORT* __restrict__ B,
             const float* __restrict__ bias, void* __restrict__ outp,
             void* __restrict__ outp2, int M, int N, int K, int lda, int ldb)
{
    __shared__ __align__(16) unsigned char smem[131072];
    const int tid = threadIdx.x;
    const int lane = tid & 63;
    const int w = tid >> 6;
    const int wr = w >> 2;
    const int wc = w & 3;

    const int gx = gridDim.x;
    const int pid = blockIdx.y * gx + blockIdx.x;
    const int nwg = gx * gridDim.y;
    const int cpx = nwg >> 3;
    const int s = (pid & 7) * cpx + (pid >> 3);
    const int px = s % gx;
    const int py = s / gx;
    const int tm = py * 256;
    const int tn = px * 256;

    USHORT* po = nullptr;
    if constexpr (EPI == 3) {
        const int z = blockIdx.z;
        A += (size_t)z * K;
        B += (size_t)z * K;
        po = ((z < 2) ? (USHORT*)outp : (USHORT*)outp2) + (size_t)(z & 1) * ((size_t)M * N);
    }

    const int sr = tid >> 2;
    const int su = (tid & 3) ^ ((tid >> 3) & 3);
    const USHORT* gA0 = A + (size_t)(tm + sr) * lda + su * 8;
    const USHORT* gA1 = A + (size_t)(tm + 128 + sr) * lda + su * 8;
    const USHORT* gB0 = B + (size_t)(tn + sr) * ldb + su * 8;
    const USHORT* gB1 = B + (size_t)(tn + 128 + sr) * ldb + su * 8;

    const int fr = lane & 15;
    const int quad = lane >> 4;
    const int uR = quad ^ ((fr >> 1) & 3);
    const int loff = fr * 32 + uR * 8;

    f32x4 acc[8][4];
    #pragma unroll
    for (int i = 0; i < 8; i++)
        #pragma unroll
        for (int j = 0; j < 4; j++) acc[i][j] = (f32x4){0.f, 0.f, 0.f, 0.f};

    const int NT = K >> 5;

    auto stage = [&](int t) {
        unsigned char* sb = smem + (size_t)(t & 3) * 32768;
        const size_t koff = (size_t)t * 32;
        gload_lds16(gA0 + koff, sb + w * 1024);
        gload_lds16(gA1 + koff, sb + 8192 + w * 1024);
        gload_lds16(gB0 + koff, sb + 16384 + w * 1024);
        gload_lds16(gB1 + koff, sb + 24576 + w * 1024);
    };

    stage(0);
    stage(1);

    for (int t = 0; t < NT; ++t) {
        if (t + 1 < NT) asm volatile("s_waitcnt vmcnt(4)" ::: "memory");
        else            asm volatile("s_waitcnt vmcnt(0)" ::: "memory");
        __builtin_amdgcn_s_barrier();
        if (t + 2 < NT) stage(t + 2);

        const USHORT* sA = (const USHORT*)(smem + (size_t)(t & 3) * 32768);
        const USHORT* sB = sA + 8192;
        bf16x8 a[4], b[4];
        #pragma unroll
        for (int j = 0; j < 4; j++)
            b[j] = *(const bf16x8*)(sB + (wc * 64 + j * 16) * 32 + loff);
        #pragma unroll
        for (int i = 0; i < 4; i++)
            a[i] = *(const bf16x8*)(sA + (wr * 128 + i * 16) * 32 + loff);
        __builtin_amdgcn_s_setprio(1);
        #pragma unroll
        for (int i = 0; i < 4; i++)
            #pragma unroll
            for (int j = 0; j < 4; j++)
                acc[i][j] = __builtin_amdgcn_mfma_f32_16x16x32_bf16(a[i], b[j], acc[i][j], 0, 0, 0);
        __builtin_amdgcn_s_setprio(0);
        #pragma unroll
        for (int i = 0; i < 4; i++)
            a[i] = *(const bf16x8*)(sA + (wr * 128 + 64 + i * 16) * 32 + loff);
        __builtin_amdgcn_s_setprio(1);
        #pragma unroll
        for (int i = 0; i < 4; i++)
            #pragma unroll
            for (int j = 0; j < 4; j++)
                acc[4 + i][j] = __builtin_amdgcn_mfma_f32_16x16x32_bf16(a[i], b[j], acc[4 + i][j], 0, 0, 0);
        __builtin_amdgcn_s_setprio(0);
    }

    float* eW = (float*)(smem + (size_t)w * 4352);
    const int erow = lane >> 2;
    const int ecq = lane & 3;
    const int gcolb = tn + wc * 64 + ecq * 16;
    float bb[16];
    if constexpr (EPI == 1) {
        #pragma unroll
        for (int q = 0; q < 4; q++) {
            float4 bv = *(const float4*)&bias[gcolb + q * 4];
            bb[q*4+0] = bv.x; bb[q*4+1] = bv.y; bb[q*4+2] = bv.z; bb[q*4+3] = bv.w;
        }
    }
    #pragma unroll
    for (int i = 0; i < 8; i++) {
        #pragma unroll
        for (int j = 0; j < 4; j++)
            #pragma unroll
            for (int r = 0; r < 4; r++)
                eW[(quad * 4 + r) * 68 + j * 16 + fr] = acc[i][j][r];
        float v[16];
        #pragma unroll
        for (int q = 0; q < 4; q++) {
            float4 t4 = *(const float4*)&eW[erow * 68 + ecq * 16 + q * 4];
            v[q*4+0] = t4.x; v[q*4+1] = t4.y; v[q*4+2] = t4.z; v[q*4+3] = t4.w;
        }
        const int grow = tm + wr * 128 + i * 16 + erow;
        uint32_t pk[8];
        if constexpr (EPI == 1) {
            #pragma unroll
            for (int q = 0; q < 8; q++) {
                const float z0 = v[2*q]   + bb[2*q];
                const float z1 = v[2*q+1] + bb[2*q+1];
                const float u0 = z0 * (0.7978845608f + 0.035677408f * z0 * z0);
                const float u1 = z1 * (0.7978845608f + 0.035677408f * z1 * z1);
                const float s0 = __builtin_amdgcn_rcpf(1.f + fexp2(2.885390082f * u0));
                const float s1 = __builtin_amdgcn_rcpf(1.f + fexp2(2.885390082f * u1));
                const float g0 = z0 * (1.f - s0), g1 = z1 * (1.f - s1);
                pk[q] = (uint32_t)f2bf(g0) | ((uint32_t)f2bf(g1) << 16);
            }
            USHORT* op = (USHORT*)outp + (size_t)grow * N + gcolb;
            *(uint4*)op = make_uint4(pk[0], pk[1], pk[2], pk[3]);
            *(uint4*)(op + 8) = make_uint4(pk[4], pk[5], pk[6], pk[7]);
        } else {
            #pragma unroll
            for (int q = 0; q < 8; q++)
                pk[q] = (uint32_t)f2bf(v[2*q]) | ((uint32_t)f2bf(v[2*q+1]) << 16);
            USHORT* op = po + (size_t)grow * N + gcolb;
            *(uint4*)op = make_uint4(pk[0], pk[1], pk[2], pk[3]);
            *(uint4*)(op + 8) = make_uint4(pk[4], pk[5], pk[6], pk[7]);
        }
    }
}

// ---------------- 128x256 GEMM, BK=32, ring-3 LDS 72KB (FFN2) ---------------
template<int EPI>
__global__ __launch_bounds__(512)
void gemm_tlp(const USHORT* __restrict__ A, const USHORT* __restrict__ B,
              const float* __restrict__ bias, void* __restrict__ outp,
              void* __restrict__ outp2, int M, int N, int K, int lda, int ldb)
{
    __shared__ __align__(16) unsigned char smem[73728];
    const int tid = threadIdx.x;
    const int lane = tid & 63;
    const int w = tid >> 6;
    const int wr = w >> 2;
    const int wc = w & 3;

    const int gx = gridDim.x;
    const int pid = blockIdx.y * gx + blockIdx.x;
    const int nwg = gx * gridDim.y;
    const int cpx = nwg >> 3;
    const int sw = (pid & 7) * cpx + (pid >> 3);
    const int tm = (sw % gx) * 128;
    const int tn = (sw / gx) * 256;

    USHORT* po = nullptr;
    if constexpr (EPI == 3) {
        const int z = blockIdx.z;
        A += (size_t)z * K;
        B += (size_t)z * K;
        po = ((z < 2) ? (USHORT*)outp : (USHORT*)outp2) + (size_t)(z & 1) * ((size_t)M * N);
    }

    const int srow = tid >> 2;
    const int su = (tid & 3) ^ ((tid >> 3) & 3);
    const USHORT* gA  = A + (size_t)(tm + srow) * lda + su * 8;
    const USHORT* gB0 = B + (size_t)(tn + srow) * ldb + su * 8;
    const USHORT* gB1 = B + (size_t)(tn + 128 + srow) * ldb + su * 8;

    const int fr = lane & 15;
    const int quad = lane >> 4;
    const int uR = quad ^ ((fr >> 1) & 3);
    const int loff = fr * 32 + uR * 8;

    f32x4 acc[4][4];
    #pragma unroll
    for (int i = 0; i < 4; i++)
        #pragma unroll
        for (int j = 0; j < 4; j++) acc[i][j] = (f32x4){0.f, 0.f, 0.f, 0.f};

    const int NT = K >> 5;

    auto stage = [&](int t) {
        unsigned char* sb = smem + (size_t)(t % 3) * 24576;
        const size_t ko = (size_t)t * 32;
        gload_lds16(gA  + ko, sb +         w * 1024);
        gload_lds16(gB0 + ko, sb +  8192 + w * 1024);
        gload_lds16(gB1 + ko, sb + 16384 + w * 1024);
    };

    stage(0);
    stage(1);

    for (int t = 0; t < NT; ++t) {
        if (t + 2 < NT) { stage(t + 2); asm volatile("s_waitcnt vmcnt(6)" ::: "memory"); }
        else if (t + 1 < NT) asm volatile("s_waitcnt vmcnt(3)" ::: "memory");
        else                 asm volatile("s_waitcnt vmcnt(0)" ::: "memory");
        __builtin_amdgcn_s_barrier();

        const USHORT* sA = (const USHORT*)(smem + (size_t)(t % 3) * 24576);
        const USHORT* sB = sA + 4096;
        bf16x8 a[4], b[4];
        #pragma unroll
        for (int j = 0; j < 4; j++)
            b[j] = *(const bf16x8*)(sB + (wc * 64 + j * 16) * 32 + loff);
        #pragma unroll
        for (int i = 0; i < 4; i++)
            a[i] = *(const bf16x8*)(sA + (wr * 64 + i * 16) * 32 + loff);
        __builtin_amdgcn_s_setprio(1);
        #pragma unroll
        for (int i = 0; i < 4; i++)
            #pragma unroll
            for (int j = 0; j < 4; j++)
                acc[i][j] = __builtin_amdgcn_mfma_f32_16x16x32_bf16(a[i], b[j], acc[i][j], 0, 0, 0);
        __builtin_amdgcn_s_setprio(0);
        __builtin_amdgcn_s_barrier();
    }

    __syncthreads();
    float* eW = (float*)(smem + (size_t)w * 4352);
    const int erow = lane >> 2;
    const int ecq = lane & 3;
    const int gcolb = tn + wc * 64 + ecq * 16;
    float bb[16];
    if constexpr (EPI == 1) {
        #pragma unroll
        for (int q = 0; q < 4; q++) {
            float4 bv = *(const float4*)&bias[gcolb + q * 4];
            bb[q*4+0] = bv.x; bb[q*4+1] = bv.y; bb[q*4+2] = bv.z; bb[q*4+3] = bv.w;
        }
    }
    #pragma unroll
    for (int i = 0; i < 4; i++) {
        #pragma unroll
        for (int j = 0; j < 4; j++)
            #pragma unroll
            for (int r = 0; r < 4; r++)
                eW[(quad * 4 + r) * 68 + j * 16 + fr] = acc[i][j][r];
        float v[16];
        #pragma unroll
        for (int q = 0; q < 4; q++) {
            float4 t4 = *(const float4*)&eW[erow * 68 + ecq * 16 + q * 4];
            v[q*4+0] = t4.x; v[q*4+1] = t4.y; v[q*4+2] = t4.z; v[q*4+3] = t4.w;
        }
        const int grow = tm + wr * 64 + i * 16 + erow;
        uint32_t pk[8];
        if constexpr (EPI == 1) {
            #pragma unroll
            for (int q = 0; q < 8; q++) {
                const float z0 = v[2*q]   + bb[2*q];
                const float z1 = v[2*q+1] + bb[2*q+1];
                const float u0 = z0 * (0.7978845608f + 0.035677408f * z0 * z0);
                const float u1 = z1 * (0.7978845608f + 0.035677408f * z1 * z1);
                const float s0 = __builtin_amdgcn_rcpf(1.f + fexp2(2.885390082f * u0));
                const float s1 = __builtin_amdgcn_rcpf(1.f + fexp2(2.885390082f * u1));
                const float g0 = z0 * (1.f - s0), g1 = z1 * (1.f - s1);
                pk[q] = (uint32_t)f2bf(g0) | ((uint32_t)f2bf(g1) << 16);
            }
            USHORT* op = (USHORT*)outp + (size_t)grow * N + gcolb;
            *(uint4*)op = make_uint4(pk[0], pk[1], pk[2], pk[3]);
            *(uint4*)(op + 8) = make_uint4(pk[4], pk[5], pk[6], pk[7]);
        } else {
            #pragma unroll
            for (int q = 0; q < 8; q++)
                pk[q] = (uint32_t)f2bf(v[2*q]) | ((uint32_t)f2bf(v[2*q+1]) << 16);
            USHORT* op = po + (size_t)grow * N + gcolb;
            *(uint4*)op = make_uint4(pk[0], pk[1], pk[2], pk[3]);
            *(uint4*)(op + 8) = make_uint4(pk[4], pk[5], pk[6], pk[7]);
        }
    }
    (void)bias;
}

// ---------------- FFN2 split-K=2 reduce: out = p0+p1 + bias + extra --------
__global__ __launch_bounds__(256)
void ffn2_reduce(const USHORT* __restrict__ p, const float* __restrict__ bias,
                 const float* __restrict__ extra, float* __restrict__ out)
{
    const size_t PS = (size_t)4096 * 1024;
    const size_t i = ((size_t)blockIdx.x * 256 + threadIdx.x) * 4;
    ushort4 a = *(const ushort4*)(p + i);
    ushort4 b = *(const ushort4*)(p + PS + i);
    float4 bv = *(const float4*)(bias + (i & 1023));
    float4 ev = *(const float4*)(extra + i);
    float4 o;
    o.x = b2f(a.x) + b2f(b.x) + bv.x + ev.x;
    o.y = b2f(a.y) + b2f(b.y) + bv.y + ev.y;
    o.z = b2f(a.z) + b2f(b.z) + bv.z + ev.z;
    o.w = b2f(a.w) + b2f(b.w) + bv.w + ev.w;
    *(float4*)(out + i) = o;
}

// ---------------- bc = xn @ Wbc^T + bbc: 16 tokens/block, 256 blocks --------
// Ring-2 LDS double-buffer, 1-tile-ahead prefetch with vmcnt(1), ONE barrier
// per K-iter.  Wave roles: w0 stages B rows 0-15, w1 B rows 16-31, w2 A rows;
// w0 computes (2 MFMA 16x16x32 per iter) and writes the epilogue.
__global__ __launch_bounds__(256)
void bc_mfma(const USHORT* __restrict__ xn, const USHORT* __restrict__ WbcB,
             const float* __restrict__ bbc, float* __restrict__ bc)
{
    __shared__ __align__(16) USHORT Bs[2][32 * 32];   // 2 KB each
    __shared__ __align__(16) USHORT As[2][16 * 32];   // 1 KB each
    const int tid = threadIdx.x;
    const int lane = tid & 63;
    const int w = tid >> 6;
    const int tok0 = blockIdx.x * 16;

    const int fr = lane & 15;
    const int fko = (lane >> 4) * 8;
    const int quad = lane >> 4;

    const int srow = lane >> 2;          // 0..15
    const int scol = (lane & 3) * 8;
    const USHORT* gsrc = nullptr;
    USHORT* ld0 = nullptr; USHORT* ld1 = nullptr;
    if (w == 0)      { gsrc = WbcB + (size_t)srow * 1024 + scol;         ld0 = &Bs[0][0];   ld1 = &Bs[1][0]; }
    else if (w == 1) { gsrc = WbcB + (size_t)(16 + srow) * 1024 + scol;  ld0 = &Bs[0][512]; ld1 = &Bs[1][512]; }
    else if (w == 2) { gsrc = xn + (size_t)(tok0 + srow) * 1024 + scol;  ld0 = &As[0][0];   ld1 = &As[1][0]; }

    f32x4 acc[2];
    acc[0] = (f32x4){0.f, 0.f, 0.f, 0.f};
    acc[1] = (f32x4){0.f, 0.f, 0.f, 0.f};

    if (w < 3) gload_lds16(gsrc, ld0);               // k-tile 0 -> buf 0
    for (int t = 0; t < 32; ++t) {
        if (t + 1 < 32) {
            if (w < 3) gload_lds16(gsrc + (t + 1) * 32, ((t + 1) & 1) ? ld1 : ld0);
            asm volatile("s_waitcnt vmcnt(1)" ::: "memory");   // tile t landed
        } else {
            asm volatile("s_waitcnt vmcnt(0)" ::: "memory");
        }
        __syncthreads();
        if (w == 0) {
            const USHORT* Ab = &As[t & 1][0];
            const USHORT* Bb = &Bs[t & 1][0];
            bf16x8 af = *(const bf16x8*)(Ab + fr * 32 + fko);
            bf16x8 b0 = *(const bf16x8*)(Bb + fr * 32 + fko);
            bf16x8 b1 = *(const bf16x8*)(Bb + (16 + fr) * 32 + fko);
            acc[0] = __builtin_amdgcn_mfma_f32_16x16x32_bf16(af, b0, acc[0], 0, 0, 0);
            acc[1] = __builtin_amdgcn_mfma_f32_16x16x32_bf16(af, b1, acc[1], 0, 0, 0);
        }
    }

    if (w == 0) {
        #pragma unroll
        for (int j = 0; j < 2; j++) {
            const int col = j * 16 + fr;
            const float bv = bbc[col];
            #pragma unroll
            for (int r = 0; r < 4; r++)
                bc[(size_t)(tok0 + quad * 4 + r) * 32 + col] = acc[j][r] + bv;
        }
    }
}

// ---------------- selective scan v3: chunked parallel, lane=h, n in regs ----
#define SCAN_P 64
#define SCAN_T 32

__global__ __launch_bounds__(256)
void scan_pass1(const USHORT* __restrict__ xn, const float* __restrict__ delta,
                const float* __restrict__ bc, const float* __restrict__ Alog,
                float* __restrict__ sEnd, float* __restrict__ Ptot)
{
    const int tid = threadIdx.x;
    const int h = blockIdx.x * 256 + tid;
    const int b = blockIdx.y;
    const int p = blockIdx.z;
    const size_t tok0 = (size_t)b * 2048 + p * SCAN_T;

    __shared__ __align__(16) float sBC[SCAN_T][32];
    {
        int t = tid >> 3, q = (tid & 7) * 4;
        *(float4*)&sBC[t][q] = *(const float4*)(bc + (tok0 + t) * 32 + q);
    }

    float en[16], s[16], P[16];
    #pragma unroll
    for (int k = 0; k < 4; k++) {
        float4 a = *(const float4*)(Alog + h * 16 + k * 4);
        en[k*4+0] = -__expf(a.x) * 1.44269504f;
        en[k*4+1] = -__expf(a.y) * 1.44269504f;
        en[k*4+2] = -__expf(a.z) * 1.44269504f;
        en[k*4+3] = -__expf(a.w) * 1.44269504f;
    }
    #pragma unroll
    for (int n = 0; n < 16; n++) { s[n] = 0.f; P[n] = 1.f; }
    __syncthreads();

    const float* dp = delta + tok0 * 1024 + h;
    const USHORT* xp = xn + tok0 * 1024 + h;
    float d_c = dp[0];
    USHORT x_c = xp[0];
    for (int t = 0; t < SCAN_T; ++t) {
        const int tn = (t < SCAN_T - 1) ? t + 1 : t;
        float d_n = dp[(size_t)tn * 1024];
        USHORT x_n = xp[(size_t)tn * 1024];
        const float dx = d_c * b2f(x_c);
        #pragma unroll
        for (int k = 0; k < 4; k++) {
            float4 Bv = *(const float4*)&sBC[t][k*4];
            float bb[4] = { Bv.x, Bv.y, Bv.z, Bv.w };
            #pragma unroll
            for (int j = 0; j < 4; j++) {
                const int n = k*4 + j;
                const float dA = fexp2(d_c * en[n]);
                s[n] = fmaf(dA, s[n], dx * bb[j]);
                P[n] *= dA;
            }
        }
        d_c = d_n; x_c = x_n;
    }

    const size_t off = (size_t)p * 32768 + ((size_t)b * 1024 + h) * 16;
    #pragma unroll
    for (int k = 0; k < 4; k++) {
        *(float4*)(sEnd + off + k*4) = (float4){ s[k*4], s[k*4+1], s[k*4+2], s[k*4+3] };
        *(float4*)(Ptot + off + k*4) = (float4){ P[k*4], P[k*4+1], P[k*4+2], P[k*4+3] };
    }
}

__global__ __launch_bounds__(256)
void scan_mid(const float* __restrict__ sEnd, const float* __restrict__ Ptot,
              float* __restrict__ sIn)
{
    const int L = blockIdx.x * 256 + threadIdx.x;
    float s = 0.f;
    #pragma unroll 8
    for (int p = 0; p < SCAN_P; ++p) {
        const size_t off = (size_t)p * 32768 + L;
        sIn[off] = s;
        s = fmaf(Ptot[off], s, sEnd[off]);
    }
}

__global__ __launch_bounds__(256)
void scan_pass2(const float* __restrict__ x, const USHORT* __restrict__ xn,
                const float* __restrict__ delta, const float* __restrict__ bc,
                const float* __restrict__ Alog, const float* __restrict__ Dp,
                const float* __restrict__ sIn, float* __restrict__ ssm)
{
    const int tid = threadIdx.x;
    const int h = blockIdx.x * 256 + tid;
    const int b = blockIdx.y;
    const int p = blockIdx.z;
    const size_t tok0 = (size_t)b * 2048 + p * SCAN_T;

    __shared__ __align__(16) float sBC[SCAN_T][32];
    {
        int t = tid >> 3, q = (tid & 7) * 4;
        *(float4*)&sBC[t][q] = *(const float4*)(bc + (tok0 + t) * 32 + q);
    }

    float en[16], s[16];
    #pragma unroll
    for (int k = 0; k < 4; k++) {
        float4 a = *(const float4*)(Alog + h * 16 + k * 4);
        en[k*4+0] = -__expf(a.x) * 1.44269504f;
        en[k*4+1] = -__expf(a.y) * 1.44269504f;
        en[k*4+2] = -__expf(a.z) * 1.44269504f;
        en[k*4+3] = -__expf(a.w) * 1.44269504f;
    }
    const size_t off = (size_t)p * 32768 + ((size_t)b * 1024 + h) * 16;
    #pragma unroll
    for (int k = 0; k < 4; k++) {
        float4 v = *(const float4*)(sIn + off + k*4);
        s[k*4] = v.x; s[k*4+1] = v.y; s[k*4+2] = v.z; s[k*4+3] = v.w;
    }
    const float Dv = Dp[h];
    __syncthreads();

    const float* dp = delta + tok0 * 1024 + h;
    const USHORT* xp = xn + tok0 * 1024 + h;
    const float* xrp = x + tok0 * 1024 + h;
    float* op = ssm + tok0 * 1024 + h;

    float d_c = dp[0];
    USHORT x_c = xp[0];
    float xr_c = xrp[0];
    for (int t = 0; t < SCAN_T; ++t) {
        const int tn = (t < SCAN_T - 1) ? t + 1 : t;
        float d_n = dp[(size_t)tn * 1024];
        USHORT x_n = xp[(size_t)tn * 1024];
        float xr_n = xrp[(size_t)tn * 1024];
        const float xv = b2f(x_c);
        const float dx = d_c * xv;
        float y = 0.f;
        #pragma unroll
        for (int k = 0; k < 4; k++) {
            float4 Bv = *(const float4*)&sBC[t][k*4];
            float4 Cv = *(const float4*)&sBC[t][16 + k*4];
            float bb[4] = { Bv.x, Bv.y, Bv.z, Bv.w };
            float cc[4] = { Cv.x, Cv.y, Cv.z, Cv.w };
            #pragma unroll
            for (int j = 0; j < 4; j++) {
                const int n = k*4 + j;
                const float dA = fexp2(d_c * en[n]);
                s[n] = fmaf(dA, s[n], dx * bb[j]);
                y = fmaf(cc[j], s[n], y);
            }
        }
        op[(size_t)t * 1024] = xr_c + y + Dv * xv;
        d_c = d_n; x_c = x_n; xr_c = xr_n;
    }
}

extern "C" void kernel_launch(void* const* d_in, const int* in_sizes, int n_in,
                              void* d_out, int out_size, void* d_ws, size_t ws_size,
                              hipStream_t stream)
{
    const float* x    = (const float*)d_in[0];
    const float* ln1g = (const float*)d_in[1];
    const float* ln1b = (const float*)d_in[2];
    const float* Wd   = (const float*)d_in[3];
    const float* bd   = (const float*)d_in[4];
    const float* Wbc  = (const float*)d_in[5];
    const float* bbc  = (const float*)d_in[6];
    const float* Alog = (const float*)d_in[7];
    const float* Dp   = (const float*)d_in[8];
    const float* ln2g = (const float*)d_in[9];
    const float* ln2b = (const float*)d_in[10];
    const float* W1   = (const float*)d_in[11];
    const float* b1   = (const float*)d_in[12];
    const float* W2   = (const float*)d_in[13];
    const float* b2   = (const float*)d_in[14];
    float* out = (float*)d_out;

    char* ws = (char*)d_ws;
    const size_t MB = 1024 * 1024;
    float*  deltaW = (float*)(ws + 0);            // 16 MiB (4096x1024 f32)
    float*  ssmW   = (float*)(ws + 16 * MB);      // 16 MiB (4096x1024 f32)
    USHORT* xnW    = (USHORT*)(ws + 32 * MB);     //  8 MiB (4096x1024 bf16)
    USHORT* nrmW   = (USHORT*)(ws + 40 * MB);     //  8 MiB (4096x1024 bf16)
    USHORT* hffW   = (USHORT*)(ws + 48 * MB);     // 32 MiB (4096x4096 bf16)
    float*  bcW    = (float*)(ws + 80 * MB);      // 512 KiB (4096x32 f32)
    USHORT* WdB    = (USHORT*)(ws + 81 * MB);     //  2 MiB (1024x1024 bf16)
    USHORT* W1B    = (USHORT*)(ws + 83 * MB);     //  8 MiB (4096x1024 bf16)
    USHORT* W2B    = (USHORT*)(ws + 91 * MB);     //  8 MiB (1024x4096 bf16)
    USHORT* WbcB   = (USHORT*)(ws + 99 * MB);     // 64 KiB (32x1024 bf16)
    // scan scratch aliases hffW (dead until FFN1): 3 x 8 MiB
    float*  sEndW  = (float*)(ws + 48 * MB);
    float*  PtotW  = (float*)(ws + 56 * MB);
    float*  sInW   = (float*)(ws + 64 * MB);
    // FFN2 split-K=2 partials alias deltaW (delta dead after scan_pass2)
    USHORT* ffn2p  = (USHORT*)(ws + 0);           // 16 MiB: 2 x 4096x1024 bf16

    // 0. convert all weights f32 -> bf16 (single fused launch)
    f2b_all<<<9248, 256, 0, stream>>>(Wd, W1, W2, Wbc, WdB, W1B, W2B, WbcB);
    // 1. xn = LN1(x)                         (bf16), wave-per-token
    ln_kernel<<<1024, 256, 0, stream>>>(x, ln1g, ln1b, xnW);
    // 2. delta = softplus(xn @ Wd^T + bd)    (f32), fused epilogue
    gemm_bt<2><<<dim3(8, 32), 256, 0, stream>>>(xnW, WdB, bd, deltaW, nullptr, 4096, 1024, 1024, 1024, 1024);
    // 3. bc = xn @ Wbc^T + bbc               (f32), 256-block prefetched MFMA
    bc_mfma<<<256, 256, 0, stream>>>(xnW, WbcB, bbc, bcW);
    // 4. ssm_out = x + scan(...) + D*xn      (f32), chunked parallel scan
    scan_pass1<<<dim3(4, 2, SCAN_P), 256, 0, stream>>>(xnW, deltaW, bcW, Alog, sEndW, PtotW);
    scan_mid<<<128, 256, 0, stream>>>(sEndW, PtotW, sInW);
    scan_pass2<<<dim3(4, 2, SCAN_P), 256, 0, stream>>>(x, xnW, deltaW, bcW, Alog, Dp, sInW, ssmW);
    // 5. normed = LN2(ssm_out)               (bf16)
    ln_kernel<<<1024, 256, 0, stream>>>(ssmW, ln2g, ln2b, nrmW);
    // 6. hff = gelu(normed @ W1^T + b1)      (bf16), gemm256 R1-best
    gemm256<1><<<dim3(16, 16), 512, 0, stream>>>(nrmW, W1B, b1, hffW, nullptr, 4096, 4096, 1024, 1024, 1024);
    // 7a. FFN2 split-K=2 partials            (bf16), gemm_tlp, 256 blocks
    gemm_tlp<3><<<dim3(32, 4, 2), 512, 0, stream>>>(hffW, W2B, nullptr, ffn2p, nullptr, 4096, 1024, 2048, 4096, 4096);
    // 7b. out = p0+p1 + b2 + ssm_out         (f32)
    ffn2_reduce<<<4096, 256, 0, stream>>>(ffn2p, b2, ssmW, out);

    (void)in_sizes; (void)n_in; (void)out_size; (void)ws_size;
}